// Round 3
// baseline (354.956 us; speedup 1.0000x reference)
//
#include <hip/hip_runtime.h>
#include <stdint.h>

// One wave (64 lanes) per batch row. B=16384 rows, T=4096 int32 each.
// Phase 1: 16 coalesced int4 loads (1KB/wave-instr) cover the row; for each
//          load, 4 ballots give the 256-element chunk mask in INTERLEAVED
//          form (word c, bit i  <->  element 256*j + 4*i + c). Chunk j's 4
//          words land on lane j via predicated move.
// Phase 2: lanes 0..15 each summarize their 256-element chunk by running the
//          run-length bit tricks directly in the interleaved representation
//          (shift-by-1 in element space == rotate components + shift word 0).
// Phase 3: 4-step shfl_down merge of the run-length monoid {ch,cl,lead,trail}.
// Phase 4: lane 0 applies exp-decay adjustment + clip, one store per row.

#define NROWS 16384
#define TLEN  4096

__global__ __launch_bounds__(256, 4) void yawn_adjust_kernel(
    const float* __restrict__ drows,
    const int4* __restrict__ gest4,
    float* __restrict__ out)
{
    const int lane = threadIdx.x & 63;
    const int row  = blockIdx.x * 4 + (threadIdx.x >> 6);

    const int4* gp = gest4 + (size_t)row * (TLEN / 4) + lane;

    // ---- Phase 1: two batches of 8 int4 loads (8KB in flight per wave).
    uint64_t m0 = 0, m1 = 0, m2 = 0, m3 = 0;   // this lane's chunk words
    #pragma unroll
    for (int g = 0; g < 2; ++g) {
        int4 v[8];
        #pragma unroll
        for (int k = 0; k < 8; ++k)
            v[k] = gp[(g * 8 + k) * 64];        // coalesced: 1KB per wave-load
        #pragma unroll
        for (int k = 0; k < 8; ++k) {
            const int j = g * 8 + k;
            uint64_t b0 = __ballot(v[k].x == 2);  // elems 256j+4i+0
            uint64_t b1 = __ballot(v[k].y == 2);  // elems 256j+4i+1
            uint64_t b2 = __ballot(v[k].z == 2);  // elems 256j+4i+2
            uint64_t b3 = __ballot(v[k].w == 2);  // elems 256j+4i+3
            if (lane == j) { m0 = b0; m1 = b1; m2 = b2; m3 = b3; }
        }
    }

    // ---- Phase 2: leaf summary of a 256-element chunk, interleaved rep.
    uint64_t allw = m0 & m1 & m2 & m3;
    bool full = (allw == ~0ull);
    uint64_t z  = ~allw;                    // word-bit i set iff any comp has a 0
    uint64_t zs = full ? 1ull : z;          // keep ctz/clz defined
    int iF = __builtin_ctzll(zs);           // first word-bit containing a zero
    int iL = 63 - __builtin_clzll(zs);      // last  word-bit containing a zero
    int cF = ((~m0 >> iF) & 1) ? 0 : ((~m1 >> iF) & 1) ? 1 : ((~m2 >> iF) & 1) ? 2 : 3;
    int cL = ((~m3 >> iL) & 1) ? 3 : ((~m2 >> iL) & 1) ? 2 : ((~m1 >> iL) & 1) ? 1 : 0;
    int lead  = full ? 256 : (4 * iF + cF);       // initial-ones run length
    int ez    = 4 * iL + cL;                      // last zero element
    int trail = full ? 256 : (255 - ez);          // final-ones run length

    // clear boundary runs -> interior mask
    uint64_t lowbits  = (1ull << iF) - 1;         // word-bits < iF
    uint64_t lowF     = 1ull << iF;
    uint64_t highbits = ~((2ull << iL) - 1);      // word-bits > iL (iL=63 -> 0)
    uint64_t highF    = 1ull << iL;
    uint64_t i0 = full ? 0ull : (m0 & ~(lowbits | ((0 < cF) ? lowF : 0) | highbits | ((0 > cL) ? highF : 0)));
    uint64_t i1 = full ? 0ull : (m1 & ~(lowbits | ((1 < cF) ? lowF : 0) | highbits | ((1 > cL) ? highF : 0)));
    uint64_t i2 = full ? 0ull : (m2 & ~(lowbits | ((2 < cF) ? lowF : 0) | highbits | ((2 > cL) ? highF : 0)));
    uint64_t i3 = full ? 0ull : (m3 & ~(lowbits | ((3 < cF) ? lowF : 0) | highbits | ((3 > cL) ? highF : 0)));

    // runs >= 4:  w = M & M>>1 & M>>2 & M>>3 (element-space shifts)
    uint64_t h0 = i0 >> 1, h1 = i1 >> 1, h2 = i2 >> 1;
    uint64_t w0 = i0 & i1 & i2 & i3;
    uint64_t w1 = i1 & i2 & i3 & h0;
    uint64_t w2 = i2 & i3 & h0 & h1;
    uint64_t w3 = i3 & h0 & h1 & h2;
    // runs >= 7:  u = w & (w>>3);  (w>>3) = (w3, w0>>1, w1>>1, w2>>1)
    uint64_t u0 = w0 & w3;
    uint64_t u1 = w1 & (w0 >> 1);
    uint64_t u2 = w2 & (w1 >> 1);
    uint64_t u3 = w3 & (w2 >> 1);
    // run starts: s = x & ~(x<<1);  (x<<1) = (x3<<1, x0, x1, x2)
    int ch = __builtin_popcountll(w0 & ~(w3 << 1)) + __builtin_popcountll(w1 & ~w0)
           + __builtin_popcountll(w2 & ~w1)        + __builtin_popcountll(w3 & ~w2);
    int cl = __builtin_popcountll(u0 & ~(u3 << 1)) + __builtin_popcountll(u1 & ~u0)
           + __builtin_popcountll(u2 & ~u1)        + __builtin_popcountll(u3 & ~u2);

    // ---- Phase 3: merge 16 chunk summaries (lanes 0..15 carry real data;
    // garbage in higher lanes never reaches lane 0's dependency cone).
    #pragma unroll
    for (int off = 1, len = 256; off < 16; off <<= 1, len <<= 1) {
        int bch    = __shfl_down(ch,    (unsigned)off, 64);
        int bcl    = __shfl_down(cl,    (unsigned)off, 64);
        int blead  = __shfl_down(lead,  (unsigned)off, 64);
        int btrail = __shfl_down(trail, (unsigned)off, 64);

        bool afull = (lead  == len);
        bool bfull = (blead == len);
        int junction = trail + blead;              // run spanning the seam
        bool interior = (!afull) && (!bfull);
        ch += bch + ((interior && junction >= 4) ? 1 : 0);
        cl += bcl + ((interior && junction >= 7) ? 1 : 0);
        lead  = afull ? (len + blead) : lead;
        trail = bfull ? (len + trail) : btrail;
    }

    // ---- Phase 4: finalize + epilogue (lane 0 only).
    if (lane == 0) {
        int hc, lc;
        if (lead == TLEN) {            // entire row is one run
            hc = 1; lc = 1;
        } else {
            hc = ch + (lead >= 4 ? 1 : 0) + (trail >= 4 ? 1 : 0);
            lc = cl + (lead >= 7 ? 1 : 0) + (trail >= 7 ? 1 : 0);
        }
        float hadj = (hc >= 2) ? 0.18f * expf(-0.5f * (float)(hc - 2)) : 0.0f;
        float ladj = (lc >= 3) ? 0.05f * expf(-0.5f * (float)(lc - 3)) : 0.0f;
        float tot  = fminf(hadj + ladj, 0.35f);
        float r    = drows[row] + tot;
        out[row]   = fminf(fmaxf(r, 0.0f), 1.0f);
    }
}

extern "C" void kernel_launch(void* const* d_in, const int* in_sizes, int n_in,
                              void* d_out, int out_size, void* d_ws, size_t ws_size,
                              hipStream_t stream) {
    (void)in_sizes; (void)n_in; (void)d_ws; (void)ws_size; (void)out_size;
    const float* drows = (const float*)d_in[0];
    const int4*  gest4 = (const int4*)d_in[1];
    float*       out   = (float*)d_out;
    dim3 grid(NROWS / 4);   // 4 waves per 256-thread block, one row per wave
    yawn_adjust_kernel<<<grid, 256, 0, stream>>>(drows, gest4, out);
}